// Round 6
// baseline (183.260 us; speedup 1.0000x reference)
//
#include <hip/hip_runtime.h>
#include <math.h>

#define S_LEN 1024
#define D_DIM 64
#define NBH   16
#define CH    128          // t-chunk width
#define NCH   8            // chunks per row
#define RPB   14           // output rows per block (16-row tile - 2 halo)
#define NSB   74           // ceil(1024/14)

typedef unsigned short ushort_t;
typedef __attribute__((ext_vector_type(8))) short short8;   // 8 bf16 (4 VGPRs)
typedef __attribute__((ext_vector_type(4))) short short4v;  // 4 bf16 (8 B)
typedef __attribute__((ext_vector_type(4))) float f32x4;

__device__ __forceinline__ ushort_t rne_bf16(float x) {
    unsigned u = __float_as_uint(x);
    return (ushort_t)((u + 0x7FFFu + ((u >> 16) & 1u)) >> 16);
}
// fp32 -> (hi, lo) bf16 pair, round-to-nearest-even.
__device__ __forceinline__ void split1(float x, ushort_t& h, ushort_t& l) {
    h = rne_bf16(x);
    float hf = __uint_as_float((unsigned)h << 16);
    l = rne_bf16(x - hf);
}

// ------------------------------ Prep ----------------------------------------
// blocks [0,1024):    K split -> QK B-frag tiled layout
//                     khi[(((bh*64+tile)*2+ch)*64+lane)*8+j], lane=quad*16+(t&15)
// blocks [1024,1280): V transpose-split -> PV B-frag tiled layout
//                     vhi[((bh*128 + (t>>3))*64 + d)*8 + (t&7)]
// blocks [1280,1344): mask -> bit-pack, mw[(b*1024+s)*32 + t/32]
__global__ __launch_bounds__(256) void prep(
    const float* __restrict__ k, const float* __restrict__ v,
    const int* __restrict__ mask,
    ushort_t* __restrict__ khi, ushort_t* __restrict__ klo,
    ushort_t* __restrict__ vhi, ushort_t* __restrict__ vlo,
    unsigned* __restrict__ mw)
{
    __shared__ float Ls[64][65];
    const int tid = threadIdx.x;
    const int bx = blockIdx.x;
    if (bx < 1024) {
        const int idx4 = bx * 256 + tid;
        const int f0 = idx4 * 4;
        const int bh = f0 >> 16;
        const int t  = (f0 >> 6) & 1023;
        const int d  = f0 & 63;
        float4 x = *(const float4*)(k + (size_t)f0);
        ushort_t h[4], l[4];
        split1(x.x, h[0], l[0]); split1(x.y, h[1], l[1]);
        split1(x.z, h[2], l[2]); split1(x.w, h[3], l[3]);
        const int ch = d >> 5, quad = (d & 31) >> 3, lane = quad * 16 + (t & 15);
        const size_t dst = ((((size_t)bh * 64 + (t >> 4)) * 2 + ch) * 64 + lane) * 8 + (d & 7);
        short4v hv = {(short)h[0], (short)h[1], (short)h[2], (short)h[3]};
        short4v lv = {(short)l[0], (short)l[1], (short)l[2], (short)l[3]};
        *(short4v*)(khi + dst) = hv;
        *(short4v*)(klo + dst) = lv;
    } else if (bx < 1280) {
        const int bi = bx - 1024;
        const int tt = bi & 15, bh = bi >> 4;
        const float* vb = v + ((size_t)bh * S_LEN + tt * 64) * D_DIM;
        #pragma unroll
        for (int p = 0; p < 4; ++p) {
            int idx = p * 1024 + tid * 4;
            int r = idx >> 6, c = idx & 63;
            float4 x = *(const float4*)(vb + r * 64 + c);
            Ls[r][c] = x.x; Ls[r][c+1] = x.y; Ls[r][c+2] = x.z; Ls[r][c+3] = x.w;
        }
        __syncthreads();
        const int d = tid >> 2, c0 = (tid & 3) * 16;
        ushort_t hi[16], lo[16];
        #pragma unroll
        for (int j = 0; j < 16; ++j) split1(Ls[c0 + j][d], hi[j], lo[j]);
        const int tb0 = tt * 8 + (c0 >> 3);
        const size_t o0 = (((size_t)bh * 128 + tb0) * 64 + d) * 8;
        const size_t o1 = (((size_t)bh * 128 + tb0 + 1) * 64 + d) * 8;
        *(short8*)(vhi + o0) = *(short8*)(hi);
        *(short8*)(vhi + o1) = *(short8*)(hi + 8);
        *(short8*)(vlo + o0) = *(short8*)(lo);
        *(short8*)(vlo + o1) = *(short8*)(lo + 8);
    } else {
        const int mi = bx - 1280;             // 0..63
        const int wv = mi * 4 + (tid >> 6);   // 0..255
        const int lane = tid & 63;
        #pragma unroll
        for (int rw = 0; rw < 8; ++rw) {
            const int row = wv * 8 + rw;      // 0..2047 = b*1024+s
            for (int it = 0; it < 16; ++it) {
                int mv = mask[(size_t)row * 1024 + it * 64 + lane];
                unsigned long long bal = __ballot(mv != 0);
                if (lane == 0) {
                    mw[row * 32 + it * 2]     = (unsigned)bal;
                    mw[row * 32 + it * 2 + 1] = (unsigned)(bal >> 32);
                }
            }
        }
    }
}

// ------------------ Fused: QK^T -> conv -> online softmax -> PV --------------
// 512 threads = 8 waves: waves 0-3 produce QK chunks, waves 4-7 conv+PV.
// dp: 3-slot ring, halo-padded (data col t at idx t+1).
// Iter j: [ QK(j) || conv(j-2) ; PV(j-3) ]  -> one barrier.
__global__ __launch_bounds__(512) void fused_attn(
    const float* __restrict__ q,
    const ushort_t* __restrict__ khi, const ushort_t* __restrict__ klo,
    const ushort_t* __restrict__ vhi, const ushort_t* __restrict__ vlo,
    const unsigned* __restrict__ mw,
    const float* __restrict__ conv_w, const float* __restrict__ conv_b,
    const float* __restrict__ lin_w, const float* __restrict__ lin_b,
    float* __restrict__ out)
{
    __shared__ float dpS[3][16][132];        // 25.3 KB
    __shared__ ushort_t pP[2][16 * 136];     // 8.7 KB, cg-stride 136 (conflict-free)
    __shared__ unsigned mb[14][32];          // 1.8 KB mask bits
    __shared__ float mS[16], lS[16];
    __shared__ float aBuf[2][16];

    const int bs = blockIdx.x, bh = blockIdx.y;
    const int s0 = bs * RPB;
    const int b  = bh >> 3;
    const int tid = threadIdx.x;
    const int wave = tid >> 6, lane = tid & 63;
    const int m = lane & 15, quad = lane >> 4;
    const bool isProd = wave < 4;

    if (tid < 16) { mS[tid] = -1e30f; lS[tid] = 0.f; }
    // mask bits -> LDS (448 words, all threads)
    for (int i = tid; i < 448; i += 512) {
        const int rr1 = i >> 5, wd = i & 31;
        const int s = s0 + rr1;               // row rr=rr1+1 -> s = s0-1+rr
        mb[rr1][wd] = (s < S_LEN) ? mw[((size_t)b * S_LEN + s) * 32 + wd] : 0u;
    }

    // conv params (uniform -> scalar regs)
    float w[36];
    #pragma unroll
    for (int i = 0; i < 36; ++i) w[i] = conv_w[i];
    float cb[4], lw[4];
    #pragma unroll
    for (int f = 0; f < 4; ++f) { cb[f] = conv_b[f]; lw[f] = lin_w[f]; }
    const float lb = lin_b[0];

    // producers: Q A-fragments (rows s0-1+m, clamped; invalid rows zeroed on write)
    short8 ahi0 = {}, alo0 = {}, ahi1 = {}, alo1 = {};
    if (isProd) {
        const int sA = s0 - 1 + m;
        const int sQ = sA < 0 ? 0 : (sA > S_LEN - 1 ? S_LEN - 1 : sA);
        const float* qp = q + ((size_t)bh * S_LEN + sQ) * D_DIM + quad * 8;
        float qa[16];
        *(float4*)(qa + 0)  = *(const float4*)(qp + 0);
        *(float4*)(qa + 4)  = *(const float4*)(qp + 4);
        *(float4*)(qa + 8)  = *(const float4*)(qp + 32);
        *(float4*)(qa + 12) = *(const float4*)(qp + 36);
        #pragma unroll
        for (int i = 0; i < 8; ++i) {
            ushort_t h, l;
            split1(qa[i], h, l);      ahi0[i] = (short)h; alo0[i] = (short)l;
            split1(qa[8 + i], h, l);  ahi1[i] = (short)h; alo1[i] = (short)l;
        }
    }

    const int tp = tid - 256;                 // consumer linear id
    const int rr = (tp < 0) ? 0 : (tp >> 4);
    const int cg = tp & 15, c0col = cg * 8;
    const bool act = (!isProd) && rr >= 1 && rr <= RPB && (s0 - 1 + rr) < S_LEN;
    const int d0 = (wave - 4) * 16;           // consumer wave's d-range

    f32x4 O = {0.f, 0.f, 0.f, 0.f};

    for (int j = 0; j <= NCH + 2; ++j) {      // 0..10
        if (isProd) {
            if (j < NCH) {
                const int slot = j % 3;
                #pragma unroll
                for (int ct = 0; ct < 2; ++ct) {
                    const int tile = j * 8 + wave * 2 + ct;
                    const size_t kb = (((size_t)bh * 64 + tile) * 128 + lane) * 8;
                    short8 bhi0 = *(const short8*)(khi + kb);
                    short8 blo0 = *(const short8*)(klo + kb);
                    short8 bhi1 = *(const short8*)(khi + kb + 512);
                    short8 blo1 = *(const short8*)(klo + kb + 512);
                    f32x4 acc = {0.f, 0.f, 0.f, 0.f};
                    acc = __builtin_amdgcn_mfma_f32_16x16x32_bf16(ahi0, bhi0, acc, 0, 0, 0);
                    acc = __builtin_amdgcn_mfma_f32_16x16x32_bf16(ahi0, blo0, acc, 0, 0, 0);
                    acc = __builtin_amdgcn_mfma_f32_16x16x32_bf16(alo0, bhi0, acc, 0, 0, 0);
                    acc = __builtin_amdgcn_mfma_f32_16x16x32_bf16(ahi1, bhi1, acc, 0, 0, 0);
                    acc = __builtin_amdgcn_mfma_f32_16x16x32_bf16(ahi1, blo1, acc, 0, 0, 0);
                    acc = __builtin_amdgcn_mfma_f32_16x16x32_bf16(alo1, bhi1, acc, 0, 0, 0);
                    const int col = wave * 32 + ct * 16 + m;
                    #pragma unroll
                    for (int r = 0; r < 4; ++r) {
                        const int br = quad * 4 + r;
                        const int s  = s0 - 1 + br;
                        const float val = (s >= 0 && s < S_LEN) ? acc[r] * 0.125f : 0.f;
                        dpS[slot][br][col + 1] = val;
                        // chunk j's col0 = right halo of chunk j-1 (slot (j-1)%3==(j+2)%3)
                        if (j >= 1 && col == 0)
                            dpS[(j + 2) % 3][br][129] = val;
                    }
                }
                if (j == 0 && wave == 0 && lane < 16) dpS[0][lane][0] = 0.f;
            }
            // left halo of chunk j-1 = chunk j-2 col127
            if (j >= 2 && j <= 8 && wave == 1 && lane < 16)
                dpS[(j - 1) % 3][lane][0] = dpS[(j - 2) % 3][lane][128];
            // right halo of final chunk = 0
            if (j == 8 && wave == 2 && lane < 16)
                dpS[(NCH - 1) % 3][lane][129] = 0.f;
        } else {
            // -------- conv + mask + online softmax on chunk c = j-2 ---------
            if (j >= 2 && j <= NCH + 1) {
                const int c = j - 2, slotC = c % 3, pc = c & 1;
                ushort_t* dst = &pP[pc][cg * 136 + rr * 8];
                if (act) {
                    float vv[3][10];
                    #pragma unroll
                    for (int dr = 0; dr < 3; ++dr) {
                        const float* rp = &dpS[slotC][rr - 1 + dr][c0col];
                        float4 a0 = *(const float4*)(rp);
                        float4 a1 = *(const float4*)(rp + 4);
                        vv[dr][0] = a0.x; vv[dr][1] = a0.y; vv[dr][2] = a0.z; vv[dr][3] = a0.w;
                        vv[dr][4] = a1.x; vv[dr][5] = a1.y; vv[dr][6] = a1.z; vv[dr][7] = a1.w;
                        vv[dr][8] = rp[8]; vv[dr][9] = rp[9];
                    }
                    const unsigned word = mb[rr - 1][c * 4 + (cg >> 2)];
                    const unsigned byt  = (word >> ((cg & 3) * 8)) & 0xffu;
                    float pre[8];
                    #pragma unroll
                    for (int i = 0; i < 8; ++i) {
                        float p = lb;
                        #pragma unroll
                        for (int f = 0; f < 4; ++f) {
                            float cv = cb[f];
                            #pragma unroll
                            for (int dr = 0; dr < 3; ++dr) {
                                cv = fmaf(w[f * 9 + dr * 3 + 0], vv[dr][i],     cv);
                                cv = fmaf(w[f * 9 + dr * 3 + 1], vv[dr][i + 1], cv);
                                cv = fmaf(w[f * 9 + dr * 3 + 2], vv[dr][i + 2], cv);
                            }
                            float a2 = fmaxf(cv, 0.f) + 0.01f * fminf(cv, 0.f);
                            p = fmaf(lw[f], a2, p);
                        }
                        pre[i] = ((byt >> i) & 1u) ? p : -1e30f;
                    }
                    float cmax = pre[0];
                    #pragma unroll
                    for (int i = 1; i < 8; ++i) cmax = fmaxf(cmax, pre[i]);
                    #pragma unroll
                    for (int off = 1; off < 16; off <<= 1)
                        cmax = fmaxf(cmax, __shfl_xor(cmax, off));
                    const float m_old = mS[rr];
                    const float m_new = fmaxf(m_old, cmax);
                    const float alpha = __expf(m_old - m_new);
                    float pv[8], ps = 0.f;
                    #pragma unroll
                    for (int i = 0; i < 8; ++i) { pv[i] = __expf(pre[i] - m_new); ps += pv[i]; }
                    #pragma unroll
                    for (int off = 1; off < 16; off <<= 1) ps += __shfl_xor(ps, off);
                    if (cg == 0) {
                        mS[rr] = m_new;
                        lS[rr] = lS[rr] * alpha + ps;
                        aBuf[pc][rr] = alpha;
                    }
                    short8 hv;
                    #pragma unroll
                    for (int i = 0; i < 8; ++i) hv[i] = (short)rne_bf16(pv[i]);
                    *(short8*)dst = hv;
                } else {
                    short8 z = {0, 0, 0, 0, 0, 0, 0, 0};
                    *(short8*)dst = z;
                    if (cg == 0) aBuf[pc][rr] = 1.f;
                }
            }
            // --------------------- PV on chunk c2 = j-3 ---------------------
            if (j >= 3) {
                const int c2 = j - 3, p2 = c2 & 1;
                #pragma unroll
                for (int r = 0; r < 4; ++r) O[r] *= aBuf[p2][quad * 4 + r];
                #pragma unroll
                for (int sb = 0; sb < 4; ++sb) {
                    short8 ph = *(const short8*)&pP[p2][(sb * 4 + quad) * 136 + m * 8];
                    const size_t vb = (((size_t)bh * 128 + c2 * 16 + sb * 4 + quad) * 64 + d0 + m) * 8;
                    short8 vh = *(const short8*)(vhi + vb);
                    short8 vl = *(const short8*)(vlo + vb);
                    O = __builtin_amdgcn_mfma_f32_16x16x32_bf16(ph, vh, O, 0, 0, 0);
                    O = __builtin_amdgcn_mfma_f32_16x16x32_bf16(ph, vl, O, 0, 0, 0);
                }
            }
        }
        __syncthreads();
    }

    // ---------------------------- epilogue ----------------------------------
    if (!isProd) {
        #pragma unroll
        for (int r = 0; r < 4; ++r) {
            const int br = quad * 4 + r;
            const int s = s0 - 1 + br;
            if (br >= 1 && br <= RPB && s < S_LEN)
                out[((size_t)bh * S_LEN + s) * D_DIM + d0 + m] = O[r] / lS[br];
        }
    }
}

extern "C" void kernel_launch(void* const* d_in, const int* in_sizes, int n_in,
                              void* d_out, int out_size, void* d_ws, size_t ws_size,
                              hipStream_t stream) {
    const float* q      = (const float*)d_in[0];
    const float* k      = (const float*)d_in[1];
    const float* v      = (const float*)d_in[2];
    const int*   mask   = (const int*)d_in[3];
    const float* conv_w = (const float*)d_in[4];
    const float* conv_b = (const float*)d_in[5];
    const float* lin_w  = (const float*)d_in[6];
    const float* lin_b  = (const float*)d_in[7];
    float* out = (float*)d_out;

    char* wsb = (char*)d_ws;
    const size_t MB = 1024 * 1024;
    ushort_t* khi = (ushort_t*)(wsb + 0 * MB);
    ushort_t* klo = (ushort_t*)(wsb + 2 * MB);
    ushort_t* vhi = (ushort_t*)(wsb + 4 * MB);
    ushort_t* vlo = (ushort_t*)(wsb + 6 * MB);
    unsigned* mw  = (unsigned*)(wsb + 8 * MB);

    prep<<<dim3(1344), 256, 0, stream>>>(k, v, mask, khi, klo, vhi, vlo, mw);
    fused_attn<<<dim3(NSB, NBH), 512, 0, stream>>>(
        q, khi, klo, vhi, vlo, mw,
        conv_w, conv_b, lin_w, lin_b, out);
}

// Round 7
// 159.561 us; speedup vs baseline: 1.1485x; 1.1485x over previous
//
#include <hip/hip_runtime.h>
#include <math.h>

#define S_LEN 1024
#define D_DIM 64
#define NBH   16
#define CH    128          // t-chunk width
#define NCH   8            // chunks per row
#define RPB   14           // output rows per block (16-row tile - 2 halo)
#define NSB   74           // ceil(1024/14)

typedef unsigned short ushort_t;
typedef __attribute__((ext_vector_type(8))) short short8;   // 8 bf16 (4 VGPRs)
typedef __attribute__((ext_vector_type(4))) short short4v;  // 4 bf16 (8 B)
typedef __attribute__((ext_vector_type(4))) float f32x4;
typedef __attribute__((ext_vector_type(2))) float f32x2;    // -> v_pk_fma_f32

__device__ __forceinline__ ushort_t rne_bf16(float x) {
    unsigned u = __float_as_uint(x);
    return (ushort_t)((u + 0x7FFFu + ((u >> 16) & 1u)) >> 16);
}
__device__ __forceinline__ void split1(float x, ushort_t& h, ushort_t& l) {
    h = rne_bf16(x);
    float hf = __uint_as_float((unsigned)h << 16);
    l = rne_bf16(x - hf);
}

// ------------------------------ Prep ----------------------------------------
// blocks [0,1024):     K split -> QK B-frag tiled layout
// blocks [1024,1280):  V transpose-split -> PV B-frag tiled layout
// blocks [1280,1536):  mask bit-pack, thread-per-word (no serial ballots)
__global__ __launch_bounds__(256) void prep(
    const float* __restrict__ k, const float* __restrict__ v,
    const int* __restrict__ mask,
    ushort_t* __restrict__ khi, ushort_t* __restrict__ klo,
    ushort_t* __restrict__ vhi, ushort_t* __restrict__ vlo,
    unsigned* __restrict__ mw)
{
    __shared__ float Ls[64][65];
    const int tid = threadIdx.x;
    const int bx = blockIdx.x;
    if (bx < 1024) {
        const int idx4 = bx * 256 + tid;
        const int f0 = idx4 * 4;
        const int bh = f0 >> 16;
        const int t  = (f0 >> 6) & 1023;
        const int d  = f0 & 63;
        float4 x = *(const float4*)(k + (size_t)f0);
        ushort_t h[4], l[4];
        split1(x.x, h[0], l[0]); split1(x.y, h[1], l[1]);
        split1(x.z, h[2], l[2]); split1(x.w, h[3], l[3]);
        const int ch = d >> 5, quad = (d & 31) >> 3, lane = quad * 16 + (t & 15);
        const size_t dst = ((((size_t)bh * 64 + (t >> 4)) * 2 + ch) * 64 + lane) * 8 + (d & 7);
        short4v hv = {(short)h[0], (short)h[1], (short)h[2], (short)h[3]};
        short4v lv = {(short)l[0], (short)l[1], (short)l[2], (short)l[3]};
        *(short4v*)(khi + dst) = hv;
        *(short4v*)(klo + dst) = lv;
    } else if (bx < 1280) {
        const int bi = bx - 1024;
        const int tt = bi & 15, bh = bi >> 4;
        const float* vb = v + ((size_t)bh * S_LEN + tt * 64) * D_DIM;
        #pragma unroll
        for (int p = 0; p < 4; ++p) {
            int idx = p * 1024 + tid * 4;
            int r = idx >> 6, c = idx & 63;
            float4 x = *(const float4*)(vb + r * 64 + c);
            Ls[r][c] = x.x; Ls[r][c+1] = x.y; Ls[r][c+2] = x.z; Ls[r][c+3] = x.w;
        }
        __syncthreads();
        const int d = tid >> 2, c0 = (tid & 3) * 16;
        ushort_t hi[16], lo[16];
        #pragma unroll
        for (int j = 0; j < 16; ++j) split1(Ls[c0 + j][d], hi[j], lo[j]);
        const int tb0 = tt * 8 + (c0 >> 3);
        const size_t o0 = (((size_t)bh * 128 + tb0) * 64 + d) * 8;
        const size_t o1 = (((size_t)bh * 128 + tb0 + 1) * 64 + d) * 8;
        *(short8*)(vhi + o0) = *(short8*)(hi);
        *(short8*)(vhi + o1) = *(short8*)(hi + 8);
        *(short8*)(vlo + o0) = *(short8*)(lo);
        *(short8*)(vlo + o1) = *(short8*)(lo + 8);
    } else {
        const int gid = (bx - 1280) * 256 + tid;   // 0..65535
        const int row = gid >> 5, wd = gid & 31;   // row = b*1024+s
        const int4* mp = (const int4*)(mask + (size_t)row * 1024 + wd * 32);
        unsigned bits = 0;
        #pragma unroll
        for (int p = 0; p < 8; ++p) {
            int4 q = mp[p];
            bits |= (q.x != 0 ? 1u : 0u) << (p * 4 + 0);
            bits |= (q.y != 0 ? 1u : 0u) << (p * 4 + 1);
            bits |= (q.z != 0 ? 1u : 0u) << (p * 4 + 2);
            bits |= (q.w != 0 ? 1u : 0u) << (p * 4 + 3);
        }
        mw[(size_t)row * 32 + wd] = bits;
    }
}

// ------------------ Fused: QK^T -> conv -> online softmax -> PV --------------
// 512 threads = 8 waves, symmetric (no specialization).
// Iter j: [ QK(j) ] barrier [ PV(j-2) ; conv(j-1) ] barrier
// QK: wave w computes 16-col tile w. conv: all 512 threads, 4 cols each.
// PV: waves 0-3 accumulate sb 0-1, waves 4-7 sb 2-3; partials merged at end.
__global__ __launch_bounds__(512) void fused_attn(
    const float* __restrict__ q,
    const ushort_t* __restrict__ khi, const ushort_t* __restrict__ klo,
    const ushort_t* __restrict__ vhi, const ushort_t* __restrict__ vlo,
    const unsigned* __restrict__ mw,
    const float* __restrict__ conv_w, const float* __restrict__ conv_b,
    const float* __restrict__ lin_w, const float* __restrict__ lin_b,
    float* __restrict__ out)
{
    __shared__ float dpS[2][16][132];        // 16.9 KB, halo: data col t at idx t+1
    __shared__ ushort_t pP[2][16 * 132];     // 8.4 KB
    __shared__ float oBuf[16][68];           // 4.4 KB epilogue merge
    __shared__ unsigned mb[14][32];          // mask bits
    __shared__ float mS[16], lS[16];
    __shared__ float aBuf[2][16];

    const int bs = blockIdx.x, bh = blockIdx.y;
    const int s0 = bs * RPB;
    const int b  = bh >> 3;
    const int tid = threadIdx.x;
    const int wave = tid >> 6, lane = tid & 63;
    const int m = lane & 15, quad = lane >> 4;

    if (tid < 16) { mS[tid] = -1e30f; lS[tid] = 0.f; }
    if (tid < 448) {
        const int rr1 = tid >> 5, wd = tid & 31;
        const int s = s0 + rr1;               // row rr=rr1+1 -> s = s0-1+rr
        mb[rr1][wd] = (s < S_LEN) ? mw[((size_t)b * S_LEN + s) * 32 + wd] : 0u;
    }

    // conv params (uniform -> SGPRs)
    float w[36];
    #pragma unroll
    for (int i = 0; i < 36; ++i) w[i] = conv_w[i];
    float cb[4], lw[4];
    #pragma unroll
    for (int f = 0; f < 4; ++f) { cb[f] = conv_b[f]; lw[f] = lin_w[f]; }
    const float lb = lin_b[0];

    // Q A-fragments (rows s0-1+m, clamped; invalid rows zeroed at dp write)
    const int sA = s0 - 1 + m;
    const int sQ = sA < 0 ? 0 : (sA > S_LEN - 1 ? S_LEN - 1 : sA);
    const float* qp = q + ((size_t)bh * S_LEN + sQ) * D_DIM + quad * 8;
    float qa[16];
    *(float4*)(qa + 0)  = *(const float4*)(qp + 0);
    *(float4*)(qa + 4)  = *(const float4*)(qp + 4);
    *(float4*)(qa + 8)  = *(const float4*)(qp + 32);
    *(float4*)(qa + 12) = *(const float4*)(qp + 36);
    short8 ahi0, alo0, ahi1, alo1;
    #pragma unroll
    for (int i = 0; i < 8; ++i) {
        ushort_t h, l;
        split1(qa[i], h, l);      ahi0[i] = (short)h; alo0[i] = (short)l;
        split1(qa[8 + i], h, l);  ahi1[i] = (short)h; alo1[i] = (short)l;
    }

    // conv mapping: 512 threads -> row rr=tid>>5 (0..15), col-group cg=tid&31 (4 cols)
    const int rr = tid >> 5, cg = tid & 31;
    const bool act = rr >= 1 && rr <= RPB && (s0 - 1 + rr) < S_LEN;

    const int d0 = (wave & 3) * 16;           // PV d-range
    const int sbh = wave >> 2;                // PV sb half
    f32x4 O = {0.f, 0.f, 0.f, 0.f};

    for (int j = 0; j <= NCH + 1; ++j) {      // 0..9
        // ---------------- phase A: QK chunk j -> slot j&1 -------------------
        if (j < NCH) {
            const int slot = j & 1;
            if (tid < 16) dpS[slot][tid][0] = j ? dpS[slot ^ 1][tid][128] : 0.f;
            const int tile = j * 8 + wave;
            const size_t kb = (((size_t)bh * 64 + tile) * 2) * 512 + lane * 8;
            short8 bhi0 = *(const short8*)(khi + kb);
            short8 blo0 = *(const short8*)(klo + kb);
            short8 bhi1 = *(const short8*)(khi + kb + 512);
            short8 blo1 = *(const short8*)(klo + kb + 512);
            f32x4 acc = {0.f, 0.f, 0.f, 0.f};
            acc = __builtin_amdgcn_mfma_f32_16x16x32_bf16(ahi0, bhi0, acc, 0, 0, 0);
            acc = __builtin_amdgcn_mfma_f32_16x16x32_bf16(ahi0, blo0, acc, 0, 0, 0);
            acc = __builtin_amdgcn_mfma_f32_16x16x32_bf16(alo0, bhi0, acc, 0, 0, 0);
            acc = __builtin_amdgcn_mfma_f32_16x16x32_bf16(ahi1, bhi1, acc, 0, 0, 0);
            acc = __builtin_amdgcn_mfma_f32_16x16x32_bf16(ahi1, blo1, acc, 0, 0, 0);
            acc = __builtin_amdgcn_mfma_f32_16x16x32_bf16(alo1, bhi1, acc, 0, 0, 0);
            const int col = wave * 16 + m;
            #pragma unroll
            for (int r = 0; r < 4; ++r) {
                const int br = quad * 4 + r;
                const int s  = s0 - 1 + br;
                const float val = (s >= 0 && s < S_LEN) ? acc[r] * 0.125f : 0.f;
                dpS[slot][br][col + 1] = val;
                if (j >= 1 && col == 0)
                    dpS[slot ^ 1][br][129] = val;    // right halo of chunk j-1
            }
        } else if (j == NCH) {
            if (tid < 16) dpS[(NCH - 1) & 1][tid][129] = 0.f;
        }
        __syncthreads();

        // ---------------- phase B: PV(j-2) then conv(j-1) -------------------
        if (j >= 2) {
            const int c2 = j - 2, p2 = c2 & 1;
            f32x4 al = *(const f32x4*)&aBuf[p2][quad * 4];
            #pragma unroll
            for (int r = 0; r < 4; ++r) O[r] *= al[r];
            #pragma unroll
            for (int sbi = 0; sbi < 2; ++sbi) {
                const int sb = sbh * 2 + sbi;
                short8 ph = *(const short8*)&pP[p2][m * 132 + sb * 32 + quad * 8];
                const size_t vb = (((size_t)bh * 128 + c2 * 16 + sb * 4 + quad) * 64 + d0 + m) * 8;
                short8 vh = *(const short8*)(vhi + vb);
                short8 vl = *(const short8*)(vlo + vb);
                O = __builtin_amdgcn_mfma_f32_16x16x32_bf16(ph, vh, O, 0, 0, 0);
                O = __builtin_amdgcn_mfma_f32_16x16x32_bf16(ph, vl, O, 0, 0, 0);
            }
        }
        if (j >= 1 && j <= NCH) {
            const int c = j - 1, slotC = c & 1, pc = c & 1;
            ushort_t* dst = &pP[pc][rr * 132 + cg * 4];
            if (act) {
                float vv[3][6];
                #pragma unroll
                for (int dr = 0; dr < 3; ++dr) {
                    const float* rp = &dpS[slotC][rr - 1 + dr][cg * 4];
                    f32x4 a0 = *(const f32x4*)(rp);
                    f32x2 a1 = *(const f32x2*)(rp + 4);
                    vv[dr][0] = a0.x; vv[dr][1] = a0.y; vv[dr][2] = a0.z;
                    vv[dr][3] = a0.w; vv[dr][4] = a1.x; vv[dr][5] = a1.y;
                }
                // packed conv: outputs (0,1) in pa, (2,3) in pb
                f32x2 pa = {lb, lb}, pb = {lb, lb};
                #pragma unroll
                for (int f = 0; f < 4; ++f) {
                    f32x2 ca = {cb[f], cb[f]}, cbv = ca;
                    #pragma unroll
                    for (int dr = 0; dr < 3; ++dr) {
                        #pragma unroll
                        for (int dc = 0; dc < 3; ++dc) {
                            const float wt = w[f * 9 + dr * 3 + dc];
                            f32x2 ia = {vv[dr][dc],     vv[dr][dc + 1]};
                            f32x2 ib = {vv[dr][dc + 2], vv[dr][dc + 3]};
                            ca  += wt * ia;
                            cbv += wt * ib;
                        }
                    }
                    f32x2 la = {fmaxf(ca.x, 0.f)  + 0.01f * fminf(ca.x, 0.f),
                                fmaxf(ca.y, 0.f)  + 0.01f * fminf(ca.y, 0.f)};
                    f32x2 lb2 = {fmaxf(cbv.x, 0.f) + 0.01f * fminf(cbv.x, 0.f),
                                 fmaxf(cbv.y, 0.f) + 0.01f * fminf(cbv.y, 0.f)};
                    pa += lw[f] * la;
                    pb += lw[f] * lb2;
                }
                const unsigned word = mb[rr - 1][c * 4 + (cg >> 3)];
                const unsigned nib  = (word >> ((cg & 7) * 4)) & 0xFu;
                float pre[4] = {pa.x, pa.y, pb.x, pb.y};
                #pragma unroll
                for (int i = 0; i < 4; ++i)
                    if (!((nib >> i) & 1u)) pre[i] = -1e30f;
                float cmax = fmaxf(fmaxf(pre[0], pre[1]), fmaxf(pre[2], pre[3]));
                #pragma unroll
                for (int off = 1; off < 32; off <<= 1)
                    cmax = fmaxf(cmax, __shfl_xor(cmax, off));
                const float m_old = mS[rr];
                const float m_new = fmaxf(m_old, cmax);
                const float alpha = __expf(m_old - m_new);
                float pv[4], ps = 0.f;
                #pragma unroll
                for (int i = 0; i < 4; ++i) { pv[i] = __expf(pre[i] - m_new); ps += pv[i]; }
                #pragma unroll
                for (int off = 1; off < 32; off <<= 1) ps += __shfl_xor(ps, off);
                if (cg == 0) {
                    mS[rr] = m_new;
                    lS[rr] = lS[rr] * alpha + ps;
                    aBuf[pc][rr] = alpha;
                }
                short4v hv = {(short)rne_bf16(pv[0]), (short)rne_bf16(pv[1]),
                              (short)rne_bf16(pv[2]), (short)rne_bf16(pv[3])};
                *(short4v*)dst = hv;
            } else {
                short4v z = {0, 0, 0, 0};
                *(short4v*)dst = z;
                if (cg == 0) aBuf[pc][rr] = 1.f;
            }
        }
        __syncthreads();
    }

    // ---------------------------- epilogue ----------------------------------
    if (wave < 4) {
        #pragma unroll
        for (int r = 0; r < 4; ++r) oBuf[quad * 4 + r][d0 + m] = O[r];
    }
    __syncthreads();
    if (wave >= 4) {
        #pragma unroll
        for (int r = 0; r < 4; ++r) {
            const int br = quad * 4 + r;
            const int s = s0 - 1 + br;
            if (br >= 1 && br <= RPB && s < S_LEN)
                out[((size_t)bh * S_LEN + s) * D_DIM + d0 + m] =
                    (O[r] + oBuf[br][d0 + m]) / lS[br];
        }
    }
}

extern "C" void kernel_launch(void* const* d_in, const int* in_sizes, int n_in,
                              void* d_out, int out_size, void* d_ws, size_t ws_size,
                              hipStream_t stream) {
    const float* q      = (const float*)d_in[0];
    const float* k      = (const float*)d_in[1];
    const float* v      = (const float*)d_in[2];
    const int*   mask   = (const int*)d_in[3];
    const float* conv_w = (const float*)d_in[4];
    const float* conv_b = (const float*)d_in[5];
    const float* lin_w  = (const float*)d_in[6];
    const float* lin_b  = (const float*)d_in[7];
    float* out = (float*)d_out;

    char* wsb = (char*)d_ws;
    const size_t MB = 1024 * 1024;
    ushort_t* khi = (ushort_t*)(wsb + 0 * MB);
    ushort_t* klo = (ushort_t*)(wsb + 2 * MB);
    ushort_t* vhi = (ushort_t*)(wsb + 4 * MB);
    ushort_t* vlo = (ushort_t*)(wsb + 6 * MB);
    unsigned* mw  = (unsigned*)(wsb + 8 * MB);

    prep<<<dim3(1536), 256, 0, stream>>>(k, v, mask, khi, klo, vhi, vlo, mw);
    fused_attn<<<dim3(NSB, NBH), 512, 0, stream>>>(
        q, khi, klo, vhi, vlo, mw,
        conv_w, conv_b, lin_w, lin_b, out);
}